// Round 12
// baseline (4791.084 us; speedup 1.0000x reference)
//
#include <hip/hip_runtime.h>
#include <hip/hip_cooperative_groups.h>

namespace cg = cooperative_groups;

typedef unsigned short u16;
typedef unsigned int   u32;
typedef unsigned long long u64;
typedef __attribute__((ext_vector_type(8))) short short8;
typedef __attribute__((ext_vector_type(4))) float f32x4;

#define BB   64
#define TT   256
#define II   512
#define HH   1024
#define KCB  512
#define GH   4096
#define KTOT 1536

#define BPAD 1544   // u16 elems per B row (3088 B stride)

// ws layout (float units):
//   [0 .. 6291456)        WT f32 [4096][1536] (dead after B-split)
//   [.. +131072)          h: 2 parities x (hi plane 65536 u16 + lo plane 65536 u16)
//   [.. +32768)           dist^2 [64][512] f32
//   [.. +2176)            barG: 4 groups x 17 lines x 32 u32
//   [.. +544)             barT: block-level tail barrier, 17 lines x 32 u32
#define WS_WT   0
#define WS_H    (GH*KTOT)
#define WS_DIST (WS_H + 131072)
#define WS_BARG (WS_DIST + BB*KCB)
#define WS_BART (WS_BARG + 4*17*32)

#define LD_AG(p)   __hip_atomic_load((p), __ATOMIC_RELAXED, __HIP_MEMORY_SCOPE_AGENT)
#define ST_AG(p,v) __hip_atomic_store((p), (v), __ATOMIC_RELAXED, __HIP_MEMORY_SCOPE_AGENT)

__device__ __forceinline__ float sigf(float x){ return 1.0f/(1.0f+expf(-x)); }
__device__ __forceinline__ u16 bf16r(float f){ u32 u = __float_as_uint(f); u += 0x7FFFu + ((u>>16)&1u); return (u16)(u>>16); }
__device__ __forceinline__ float bf16f(u16 h){ return __uint_as_float(((u32)h)<<16); }

// ---- per-group wave-level barrier: 2 arrivals per block per epoch ----
__device__ __forceinline__ void wv_arrive(u32* bg, int bid, int e){
    asm volatile("s_waitcnt vmcnt(0)" ::: "memory");   // this wave's sc1 stores at L3
    if ((threadIdx.x & 63) == 0) {
        u32 old = atomicAdd(bg + (bid & 7) * 32, 1u);
        if (old == (u32)(e * 64 - 1)) {                // 32 blocks x 2 waves per line
            u32 old2 = atomicAdd(bg + 8 * 32, 1u);
            if (old2 == (u32)(e * 8 - 1)) {
                #pragma unroll
                for (int gg = 0; gg < 8; ++gg)
                    ST_AG(bg + (9 + gg) * 32, (u32)e);
            }
        }
    }
}
// per-wave spin (no block sync, no fence — one block fence per step covers all)
__device__ __forceinline__ void wv_wait(u32* bg, int bid, int e){
    const u32* f = bg + (9 + (bid & 7)) * 32;
    while ((int)LD_AG(f) < e) __builtin_amdgcn_s_sleep(1);
}

// ---- block-level tail barrier (rounds 5-11 proven) ----
__device__ __forceinline__ void bar_arrive(u32* bar, int bid, int tid, int e){
    asm volatile("s_waitcnt vmcnt(0)" ::: "memory");
    __syncthreads();
    if (tid == 0) {
        u32 old = atomicAdd(bar + (bid & 7) * 32, 1u);
        if (old == (u32)(e * 32 - 1)) {
            u32 old2 = atomicAdd(bar + 8 * 32, 1u);
            if (old2 == (u32)(e * 8 - 1)) {
                #pragma unroll
                for (int gg = 0; gg < 8; ++gg)
                    ST_AG(bar + (9 + gg) * 32, (u32)e);
            }
        }
    }
}
__device__ __forceinline__ void bar_wait(u32* bar, int bid, int tid, int e){
    if (tid == 0) {
        while ((int)LD_AG(bar + (9 + (bid & 7)) * 32) < e)
            __builtin_amdgcn_s_sleep(1);
        __builtin_amdgcn_fence(__ATOMIC_ACQUIRE, "agent");
    }
    __syncthreads();
}

__global__ __launch_bounds__(512, 1)
void lstm_vq(const float* __restrict__ seq, const int* __restrict__ nit,
             const float* __restrict__ Wx, const float* __restrict__ Wh,
             const float* __restrict__ bias, const float* __restrict__ cb,
             float* __restrict__ out, float* __restrict__ ws)
{
    cg::grid_group grid = cg::this_grid();
    __shared__ __align__(16) u16 bHi[16*BPAD];   // 49408 B
    __shared__ __align__(16) u16 bLo[16*BPAD];   // 49408 B
    __shared__ __align__(16) float exs[2*8*256]; // 16384 B: [par][kslice][rloc][n]
    __shared__ int sBest;

    const int tid = threadIdx.x;
    const int l   = tid & 63;
    const int w   = tid >> 6;        // 0..7 = k-slice
    const int bid = (int)blockIdx.x;

    float* WT   = ws + WS_WT;
    u16*   hbuf = (u16*)(ws + WS_H);             // 2 parities x 131072 u16
    float* dist = ws + WS_DIST;
    u32*   barG = (u32*)(ws + WS_BARG);
    u32*   barT = (u32*)(ws + WS_BART);
    float* qz   = out + BB;
    float* uq   = out + BB + BB*HH;

    if (bid == 0) {
        for (int i = tid; i < 4*17*32 + 17*32; i += 512) ST_AG(barG + i, 0u);
    }

    // ---------------- one-time: WT[zcol][k] = W[k][zcol] ----------------
    {
        const int c0 = bid * 16;
        float* tile = (float*)bHi;               // 16 x 68 f32 scratch (pre-B-split)
        for (int kt = 0; kt < KTOT; kt += 64) {
            __syncthreads();
            #pragma unroll
            for (int ii2 = 0; ii2 < 2; ++ii2) {
                int ky = ii2*32 + (tid>>4);      // 0..63
                int cx = tid & 15;
                int kk = kt + ky;
                float v = (kk < II) ? Wx[(size_t)kk*GH + c0 + cx]
                                    : Wh[(size_t)(kk-II)*GH + c0 + cx];
                tile[cx*68 + ky] = v;
            }
            __syncthreads();
            {
                int cx = tid >> 5;               // 0..15
                int k2 = (tid & 31) * 2;         // 0..62
                WT[(size_t)(c0+cx)*KTOT + kt + k2]     = tile[cx*68 + k2];
                WT[(size_t)(c0+cx)*KTOT + kt + k2 + 1] = tile[cx*68 + k2 + 1];
            }
        }
        grid.sync();   // full fences: WT visible; orders barrier resets
    }

    // ---------------- one-time: split this block's 16 z-cols into bHi/bLo ----------------
    {
        __syncthreads();
        const int n  = tid >> 5;                              // 0..15
        const int zc = ((n>>2)<<10) + (bid<<2) + (n&3);
        const float* wr = WT + (size_t)zc*KTOT;
        for (int k = (tid&31)*8; k < KTOT; k += 256) {
            f32x4 v0 = *(const f32x4*)(wr + k);
            f32x4 v1 = *(const f32x4*)(wr + k + 4);
            short8 ph, pl;
            #pragma unroll
            for (int e = 0; e < 8; ++e) {
                float fv = (e<4) ? v0[e] : v1[e-4];
                u16 hb = bf16r(fv);
                ph[e] = (short)hb;
                pl[e] = (short)bf16r(fv - bf16f(hb));
            }
            *(short8*)&bHi[n*BPAD + k] = ph;
            *(short8*)&bLo[n*BPAD + k] = pl;
        }
        __syncthreads();
    }

    // ---------------- per-thread roles ----------------
    // gate: group g is gated by waves g and g+4; lanes 0..31: rloc = (w>>2)*8 + (l>>2)
    const int gGate = w & 3;
    const int rloc  = ((w>>2)<<3) + ((l>>2) & 7);  // 0..15 (meaningful for l<32)
    const int cc    = l & 3;
    const int hcol  = (bid<<2) + cc;
    const int myN   = nit[((gGate<<4) + rloc) & 63];

    int tmax[4];
    #pragma unroll
    for (int g = 0; g < 4; ++g) {
        int m = 0;
        for (int i = 0; i < 16; ++i) m = max(m, nit[g*16 + i]);
        tmax[g] = m;
    }
    const int maxNall = max(max(tmax[0], tmax[1]), max(tmax[2], tmax[3]));

    const float bi_ = bias[hcol], bf_ = bias[HH+hcol], bg_ = bias[2*HH+hcol], bo_ = bias[3*HH+hcol];

    const int arowL = l & 15;                // row within group
    const int ag    = (l>>4)<<3;             // k sub-offset within K=32 slice
    const int bn    = l & 15;                // B col this lane reads

    float cst = 0.0f;
    int par = 0;

#define XC(h0, h1, kab) { \
    short8 ph, pl; \
    _Pragma("unroll") for (int e=0;e<8;++e){ \
        float fv = (e<4) ? h0[e] : h1[e-4]; \
        u16 hb = bf16r(fv); ph[e]=(short)hb; pl[e]=(short)bf16r(fv - bf16f(hb)); } \
    int bo = bn*BPAD + (kab); \
    short8 bhv = *(const short8*)&bHi[bo]; \
    short8 blv = *(const short8*)&bLo[bo]; \
    acc0 = __builtin_amdgcn_mfma_f32_16x16x32_bf16(ph, bhv, acc0, 0,0,0); \
    acc1 = __builtin_amdgcn_mfma_f32_16x16x32_bf16(pl, bhv, acc1, 0,0,0); \
    acc2 = __builtin_amdgcn_mfma_f32_16x16x32_bf16(ph, blv, acc2, 0,0,0); }

#define HM(B, kab) { \
    int bo = bn*BPAD + (kab); \
    short8 bhv = *(const short8*)&bHi[bo]; \
    short8 blv = *(const short8*)&bLo[bo]; \
    acc0 = __builtin_amdgcn_mfma_f32_16x16x32_bf16(B##h, bhv, acc0, 0,0,0); \
    acc1 = __builtin_amdgcn_mfma_f32_16x16x32_bf16(B##l, bhv, acc1, 0,0,0); \
    acc2 = __builtin_amdgcn_mfma_f32_16x16x32_bf16(B##h, blv, acc2, 0,0,0); }

    for (int t = 0; t <= maxNall; ++t) {
        const u16* hiP = hbuf + (size_t)(t&1)*131072;        // read parity
        u16*       hiN = hbuf + (size_t)(1-(t&1))*131072;    // write parity
        u16*       loN = hiN + 65536;

        // one L1+L2 invalidate per block per step; covers all groups' h reads below
        __syncthreads();
        if (tid == 0) __builtin_amdgcn_fence(__ATOMIC_ACQUIRE, "agent");
        __syncthreads();

        #pragma unroll
        for (int g = 0; g < 4; ++g) {
            if (t > tmax[g]) continue;            // group retired (uniform)
            u32* bg = barG + g * (17*32);
            const int arow = (g<<4) + arowL;

            f32x4 acc0 = {0.f,0.f,0.f,0.f};
            f32x4 acc1 = {0.f,0.f,0.f,0.f};
            f32x4 acc2 = {0.f,0.f,0.f,0.f};

            // x loads in flight across the (usually empty) wait
            const float* xp = seq + (size_t)arow*(TT*II) + (size_t)t*II + (w<<6) + ag;
            f32x4 xa0 = *(const f32x4*)xp,        xa1 = *(const f32x4*)(xp + 4);
            f32x4 xb0 = *(const f32x4*)(xp + 32), xb1 = *(const f32x4*)(xp + 36);

            short8 q0h,q0l,q1h,q1l,q2h,q2l,q3h,q3l;
            if (t > 0) {
                wv_wait(bg, bid, t);              // h(g, t-1) globally stored
                const u16* hp = hiP + (size_t)arow*HH + (w<<7) + ag;
                q0h = *(const short8*)hp;        q0l = *(const short8*)(hp + 65536);
                q1h = *(const short8*)(hp + 32); q1l = *(const short8*)(hp + 32 + 65536);
                q2h = *(const short8*)(hp + 64); q2l = *(const short8*)(hp + 64 + 65536);
                q3h = *(const short8*)(hp + 96); q3l = *(const short8*)(hp + 96 + 65536);
            }

            // x GEMM (2 iters) — cvt VALU covers h-load latency
            XC(xa0, xa1, (w<<6) + ag);
            XC(xb0, xb1, (w<<6) + 32 + ag);
            if (t > 0) {
                HM(q0, 512 + (w<<7) + ag);
                HM(q1, 512 + (w<<7) + 32 + ag);
                HM(q2, 512 + (w<<7) + 64 + ag);
                HM(q3, 512 + (w<<7) + 96 + ag);
            }

            // exchange: D (col=l&15, row=(l>>4)*4+j) -> ex[par][w][rloc][n]
            {
                const int n  = l & 15;
                const int r0 = (l>>4) << 2;
                float* exw = exs + par*2048 + w*256;
                #pragma unroll
                for (int j = 0; j < 4; ++j)
                    exw[(r0+j)*16 + n] = acc0[j] + acc1[j] + acc2[j];
            }
            __syncthreads();

            // gate: waves g and g+4, lanes 0..31 (16 rows x 4 cols, split by row-half)
            if ((w & 3) == g && l < 32) {
                const float* exb = exs + par*2048 + rloc*16 + cc;
                float z0 = bi_, z1 = bf_, z2 = bg_, z3 = bo_;
                #pragma unroll
                for (int ks = 0; ks < 8; ++ks) {
                    const float* e2 = exb + ks*256;
                    z0 += e2[0]; z1 += e2[4]; z2 += e2[8]; z3 += e2[12];
                }
                float iv = sigf(z0), fv = sigf(z1), gv = tanhf(z2), ov = sigf(z3);
                cst = fv*cst + iv*gv;
                float h = ov * tanhf(cst);
                u16 hb = bf16r(h);
                u16 lb = bf16r(h - bf16f(hb));
                const size_t hadr = (size_t)((g<<4) + rloc)*HH + hcol;
                ST_AG(&hiN[hadr], hb);
                ST_AG(&loN[hadr], lb);
                if (t == myN) ST_AG(&uq[hadr], h);
                wv_arrive(bg, bid, t + 1);        // vmcnt(0) inside; epoch t+1
            }
            par ^= 1;
        }
    }

#undef XC
#undef HM

    // ---------- tail: all uq visible, then VQ ----------
    #pragma unroll
    for (int g = 0; g < 4; ++g) wv_wait(barG + g*(17*32), bid, tmax[g] + 1);
    __syncthreads();
    if (tid == 0) __builtin_amdgcn_fence(__ATOMIC_ACQUIRE, "agent");
    __syncthreads();

    // ---------- VQ: distance^2 matrix [64][512] ----------
    {
        const int wid = bid*8 + w;
        for (int p = wid*16; p < wid*16 + 16; ++p) {
            int rr = p >> 9;
            int kk = p & 511;
            const u64* u8p = (const u64*)(uq + (size_t)rr*HH);
            const f32x4* c4 = (const f32x4*)(cb + (size_t)kk*HH);
            float s = 0.0f;
            #pragma unroll
            for (int q = 0; q < 4; ++q) {
                u64 e0 = u8p[2*(l + q*64)];
                u64 e1 = u8p[2*(l + q*64) + 1];
                f32x4 b = c4[l + q*64];
                float a0 = __uint_as_float((u32)e0), a1 = __uint_as_float((u32)(e0>>32));
                float a2 = __uint_as_float((u32)e1), a3 = __uint_as_float((u32)(e1>>32));
                float d0 = a0-b[0], d1 = a1-b[1], d2 = a2-b[2], d3 = a3-b[3];
                s += d0*d0 + d1*d1 + d2*d2 + d3*d3;
            }
            #pragma unroll
            for (int off = 32; off > 0; off >>= 1) s += __shfl_xor(s, off, 64);
            if (l == 0) ST_AG(&dist[(size_t)rr*KCB + kk], s);
        }
    }
    bar_arrive(barT, bid, tid, 1);
    bar_wait(barT, bid, tid, 1);      // fence inside -> plain dist reads OK

    // ---------- argmin + emit outputs (blocks 0..63, one row each) ----------
    if (bid < BB) {
        const int rr = bid;
        if (tid < 64) {
            float best = 3.4e38f;
            int   bi   = 0;
            for (int kk = tid; kk < KCB; kk += 64) {
                float v = dist[(size_t)rr*KCB + kk];
                if (v < best) { best = v; bi = kk; }
            }
            #pragma unroll
            for (int off = 32; off > 0; off >>= 1) {
                float ovv = __shfl_xor(best, off, 64);
                int   oii = __shfl_xor(bi,   off, 64);
                if (ovv < best || (ovv == best && oii < bi)) { best = ovv; bi = oii; }
            }
            if (tid == 0) { sBest = bi; out[rr] = (float)bi; }
        }
        __syncthreads();
        const int bk = sBest;
        const f32x4* c4 = (const f32x4*)(cb + (size_t)bk*HH);
        f32x4*       q4 = (f32x4*)(qz + (size_t)rr*HH);
        for (int d = tid; d < HH/4; d += 512) q4[d] = c4[d];
    }
}

extern "C" void kernel_launch(void* const* d_in, const int* in_sizes, int n_in,
                              void* d_out, int out_size, void* d_ws, size_t ws_size,
                              hipStream_t stream) {
    const float* seq  = (const float*)d_in[0];
    const int*   nit  = (const int*)  d_in[1];
    const float* Wx   = (const float*)d_in[2];
    const float* Wh   = (const float*)d_in[3];
    const float* bias = (const float*)d_in[4];
    const float* cb   = (const float*)d_in[5];
    float* out = (float*)d_out;
    float* ws  = (float*)d_ws;

    void* args[] = { &seq, &nit, &Wx, &Wh, &bias, &cb, &out, &ws };
    hipLaunchCooperativeKernel((void*)lstm_vq, dim3(256), dim3(512), args, 0, stream);
}

// Round 13
// 3647.290 us; speedup vs baseline: 1.3136x; 1.3136x over previous
//
#include <hip/hip_runtime.h>
#include <hip/hip_cooperative_groups.h>

namespace cg = cooperative_groups;

typedef unsigned short u16;
typedef unsigned int   u32;
typedef unsigned long long u64;
typedef __attribute__((ext_vector_type(8))) short short8;
typedef __attribute__((ext_vector_type(4))) float f32x4;

#define BB   64
#define TT   256
#define II   512
#define HH   1024
#define KCB  512
#define GH   4096
#define KTOT 1536

#define BPAD 1544   // u16 elems per B row (3088 B stride)

// ws layout (float units):
//   [0 .. 6291456)        WT f32 [4096][1536] (dead after B-split)
//   [.. +131072)          h: 2 parities x (hi plane 65536 u16 + lo plane 65536 u16)
//   [.. +32768)           dist^2 [64][512] f32
//   [.. +2304)            barC: 8 chunks x (1 arrival + 8 goflag) lines x 32 u32
//   [.. +544)             barT: tail barrier, 17 lines x 32 u32
#define WS_WT   0
#define WS_H    (GH*KTOT)
#define WS_DIST (WS_H + 131072)
#define WS_BARC (WS_DIST + BB*KCB)
#define WS_BART (WS_BARC + 8*9*32)

#define LD_AG(p)   __hip_atomic_load((p), __ATOMIC_RELAXED, __HIP_MEMORY_SCOPE_AGENT)
#define ST_AG(p,v) __hip_atomic_store((p), (v), __ATOMIC_RELAXED, __HIP_MEMORY_SCOPE_AGENT)

__device__ __forceinline__ float sigf(float x){ return 1.0f/(1.0f+expf(-x)); }
__device__ __forceinline__ u16 bf16r(float f){ u32 u = __float_as_uint(f); u += 0x7FFFu + ((u>>16)&1u); return (u16)(u>>16); }
__device__ __forceinline__ float bf16f(u16 h){ return __uint_as_float(((u32)h)<<16); }

// ---- block-level tail barrier (rounds 5-11 proven) ----
__device__ __forceinline__ void bar_arrive(u32* bar, int bid, int tid, int e){
    asm volatile("s_waitcnt vmcnt(0)" ::: "memory");
    __syncthreads();
    if (tid == 0) {
        u32 old = atomicAdd(bar + (bid & 7) * 32, 1u);
        if (old == (u32)(e * 32 - 1)) {
            u32 old2 = atomicAdd(bar + 8 * 32, 1u);
            if (old2 == (u32)(e * 8 - 1)) {
                #pragma unroll
                for (int gg = 0; gg < 8; ++gg)
                    ST_AG(bar + (9 + gg) * 32, (u32)e);
            }
        }
    }
}
__device__ __forceinline__ void bar_wait(u32* bar, int bid, int tid, int e){
    if (tid == 0) {
        while ((int)LD_AG(bar + (9 + (bid & 7)) * 32) < e)
            __builtin_amdgcn_s_sleep(1);
        __builtin_amdgcn_fence(__ATOMIC_ACQUIRE, "agent");
    }
    __syncthreads();
}

__global__ __launch_bounds__(512, 1)
void lstm_vq(const float* __restrict__ seq, const int* __restrict__ nit,
             const float* __restrict__ Wx, const float* __restrict__ Wh,
             const float* __restrict__ bias, const float* __restrict__ cb,
             float* __restrict__ out, float* __restrict__ ws)
{
    cg::grid_group grid = cg::this_grid();
    __shared__ __align__(16) u16 bHi[16*BPAD];   // 49408 B
    __shared__ __align__(16) u16 bLo[16*BPAD];   // 49408 B
    __shared__ __align__(16) float exs[8*1024];  // 32768 B: [kslice][row][col]
    __shared__ int sBest;

    const int tid = threadIdx.x;
    const int l   = tid & 63;
    const int w   = tid >> 6;        // 0..7 = k-slice / h-chunk owner
    const int bid = (int)blockIdx.x;

    float* WT   = ws + WS_WT;
    u16*   hbuf = (u16*)(ws + WS_H);             // 2 parities x 131072 u16
    float* dist = ws + WS_DIST;
    u32*   barC = (u32*)(ws + WS_BARC);
    u32*   barT = (u32*)(ws + WS_BART);
    float* qz   = out + BB;
    float* uq   = out + BB + BB*HH;

    if (bid == 0) {
        for (int i = tid; i < 8*9*32 + 17*32; i += 512) ST_AG(barC + i, 0u);
    }

    // ---------------- one-time: WT[zcol][k] = W[k][zcol] ----------------
    {
        const int c0 = bid * 16;
        float* tile = (float*)bHi;               // 16 x 68 f32 scratch (pre-B-split)
        for (int kt = 0; kt < KTOT; kt += 64) {
            __syncthreads();
            #pragma unroll
            for (int ii2 = 0; ii2 < 2; ++ii2) {
                int ky = ii2*32 + (tid>>4);      // 0..63
                int cx = tid & 15;
                int kk = kt + ky;
                float v = (kk < II) ? Wx[(size_t)kk*GH + c0 + cx]
                                    : Wh[(size_t)(kk-II)*GH + c0 + cx];
                tile[cx*68 + ky] = v;
            }
            __syncthreads();
            {
                int cx = tid >> 5;               // 0..15
                int k2 = (tid & 31) * 2;         // 0..62
                WT[(size_t)(c0+cx)*KTOT + kt + k2]     = tile[cx*68 + k2];
                WT[(size_t)(c0+cx)*KTOT + kt + k2 + 1] = tile[cx*68 + k2 + 1];
            }
        }
        grid.sync();   // full fences: WT visible; orders barrier resets
    }

    // ---------------- one-time: split this block's 16 z-cols into bHi/bLo ----------------
    {
        __syncthreads();
        const int n  = tid >> 5;                              // 0..15
        const int zc = ((n>>2)<<10) + (bid<<2) + (n&3);
        const float* wr = WT + (size_t)zc*KTOT;
        for (int k = (tid&31)*8; k < KTOT; k += 256) {
            f32x4 v0 = *(const f32x4*)(wr + k);
            f32x4 v1 = *(const f32x4*)(wr + k + 4);
            short8 ph, pl;
            #pragma unroll
            for (int e = 0; e < 8; ++e) {
                float fv = (e<4) ? v0[e] : v1[e-4];
                u16 hb = bf16r(fv);
                ph[e] = (short)hb;
                pl[e] = (short)bf16r(fv - bf16f(hb));
            }
            *(short8*)&bHi[n*BPAD + k] = ph;
            *(short8*)&bLo[n*BPAD + k] = pl;
        }
        __syncthreads();
    }

    // ---------------- per-thread roles ----------------
    const int rEx  = (tid & 255) >> 2;           // gate phase (tid<256)
    const int ccEx = tid & 3;
    const int hcol = (bid<<2) + ccEx;
    const int myN  = nit[rEx];
    int maxN = 0;
    for (int i = 0; i < BB; ++i) maxN = max(maxN, nit[i]);

    const float bi_ = bias[hcol], bf_ = bias[HH+hcol], bg_ = bias[2*HH+hcol], bo_ = bias[3*HH+hcol];

    const int ag   = (l>>4)<<3;              // k sub-offset within K=32 slice
    const int bn   = l & 15;                 // B col this lane reads
    const int cprod = bid >> 5;              // chunk this block produces
    u32* myArr  = barC + cprod*288;                      // arrival line
    const u32* myFlag = barC + w*288 + (1 + (bid&7))*32; // wave w polls chunk w

    float cst = 0.0f;

#define XC(P, h0, h1, kab) { \
    short8 ph, pl; \
    _Pragma("unroll") for (int e=0;e<8;++e){ \
        float fv = (e<4) ? h0[e] : h1[e-4]; \
        u16 hb = bf16r(fv); ph[e]=(short)hb; pl[e]=(short)bf16r(fv - bf16f(hb)); } \
    int bo = bn*BPAD + (kab); \
    short8 bhv = *(const short8*)&bHi[bo]; \
    short8 blv = *(const short8*)&bLo[bo]; \
    P##0 = __builtin_amdgcn_mfma_f32_16x16x32_bf16(ph, bhv, P##0, 0,0,0); \
    P##1 = __builtin_amdgcn_mfma_f32_16x16x32_bf16(pl, bhv, P##1, 0,0,0); \
    P##2 = __builtin_amdgcn_mfma_f32_16x16x32_bf16(ph, blv, P##2, 0,0,0); }

#define HM(P, B, kab) { \
    int bo = bn*BPAD + (kab); \
    short8 bhv = *(const short8*)&bHi[bo]; \
    short8 blv = *(const short8*)&bLo[bo]; \
    P##0 = __builtin_amdgcn_mfma_f32_16x16x32_bf16(B##h, bhv, P##0, 0,0,0); \
    P##1 = __builtin_amdgcn_mfma_f32_16x16x32_bf16(B##l, bhv, P##1, 0,0,0); \
    P##2 = __builtin_amdgcn_mfma_f32_16x16x32_bf16(B##h, blv, P##2, 0,0,0); }

// x phase for row-tile mt: k slice [64w, 64w+64)
#define XPH(P, mt) { \
    const float* xp_ = seq + (size_t)(((mt)<<4)+(l&15))*(TT*II) + (size_t)t*II + (w<<6) + ag; \
    f32x4 x0 = *(const f32x4*)xp_,      x1 = *(const f32x4*)(xp_+4); \
    f32x4 x2 = *(const f32x4*)(xp_+32), x3 = *(const f32x4*)(xp_+36); \
    XC(P, x0, x1, (w<<6)+ag); \
    XC(P, x2, x3, (w<<6)+32+ag); }

// h phase for row-tile mt: k slice [128w, 128w+128) = chunk w
#define HPH(P, mt) { \
    const u16* hp_ = hiP + (size_t)(((mt)<<4)+(l&15))*HH + (w<<7) + ag; \
    short8 h0h = *(const short8*)hp_,       h0l = *(const short8*)(hp_+65536); \
    short8 h1h = *(const short8*)(hp_+32),  h1l = *(const short8*)(hp_+32+65536); \
    short8 h2h = *(const short8*)(hp_+64),  h2l = *(const short8*)(hp_+64+65536); \
    short8 h3h = *(const short8*)(hp_+96),  h3l = *(const short8*)(hp_+96+65536); \
    HM(P, h0, 512+(w<<7)+ag);    HM(P, h1, 512+(w<<7)+32+ag); \
    HM(P, h2, 512+(w<<7)+64+ag); HM(P, h3, 512+(w<<7)+96+ag); }

#define EXW(P, mt) { \
    const int n_ = l & 15; \
    const int r0_ = ((mt)<<4) + ((l>>4)<<2); \
    float* e_ = exs + w*1024 + r0_*16 + n_; \
    _Pragma("unroll") for (int j=0;j<4;++j) \
        e_[j*16] = P##0[j] + P##1[j] + P##2[j]; }

    for (int t = 0; t <= maxN; ++t) {
        const u16* hiP = hbuf + (size_t)(t&1)*131072;
        u16*       hiN = hbuf + (size_t)(1-(t&1))*131072;
        u16*       loN = hiN + 65536;

        f32x4 z4 = {0.f,0.f,0.f,0.f};
        f32x4 aA0=z4,aA1=z4,aA2=z4, aB0=z4,aB1=z4,aB2=z4;
        f32x4 aC0=z4,aC1=z4,aC2=z4, aD0=z4,aD1=z4,aD2=z4;

        // ---- x GEMM: this wave's 64-k slice, all 4 row-tiles (pre-wait) ----
        XPH(aA,0) XPH(aB,1) XPH(aC,2) XPH(aD,3)

        // ---- per-wave chunk wait, then h GEMM: chunk w only (4 iters x 4 tiles) ----
        if (t > 0) {
            while ((int)LD_AG(myFlag) < t) __builtin_amdgcn_s_sleep(1);
            HPH(aA,0) HPH(aB,1) HPH(aC,2) HPH(aD,3)
        }

        // ---- exchange: wave w writes its k-slice partials ----
        EXW(aA,0) EXW(aB,1) EXW(aC,2) EXW(aD,3)
        __syncthreads();

        // ---- gate (tid<256): sum 8 k-slices + bias ----
        if (tid < 256) {
            const float* e0 = exs + rEx*16 + ccEx;
            float z0 = bi_, z1 = bf_, z2 = bg_, z3 = bo_;
            #pragma unroll
            for (int ww = 0; ww < 8; ++ww) {
                const float* e_ = e0 + ww*1024;
                z0 += e_[0]; z1 += e_[4]; z2 += e_[8]; z3 += e_[12];
            }
            float iv = sigf(z0), fv = sigf(z1), gv = tanhf(z2), ov = sigf(z3);
            cst = fv*cst + iv*gv;
            float h = ov * tanhf(cst);
            u16 hb = bf16r(h);
            u16 lb = bf16r(h - bf16f(hb));
            ST_AG(&hiN[(size_t)rEx*HH + hcol], hb);
            ST_AG(&loN[(size_t)rEx*HH + hcol], lb);
            if (t == myN) ST_AG(&uq[(size_t)rEx*HH + hcol], h);
        }

        // ---- arrive (chunk cprod) + one fence per block per step ----
        asm volatile("s_waitcnt vmcnt(0)" ::: "memory");
        __syncthreads();
        if (tid == 0) {
            u32 old = atomicAdd(myArr, 1u);
            if (old == (u32)((t+1)*32 - 1)) {
                #pragma unroll
                for (int g = 0; g < 8; ++g)
                    ST_AG(myArr + (1+g)*32, (u32)(t+1));
            }
            __builtin_amdgcn_fence(__ATOMIC_ACQUIRE, "agent");
        }
        __syncthreads();
    }

#undef XC
#undef HM
#undef XPH
#undef HPH
#undef EXW

    // ---------- tail: all chunks at epoch maxN+1, fence, then VQ ----------
    while ((int)LD_AG(myFlag) < maxN + 1) __builtin_amdgcn_s_sleep(1);
    __syncthreads();
    if (tid == 0) __builtin_amdgcn_fence(__ATOMIC_ACQUIRE, "agent");
    __syncthreads();

    // ---------- VQ: distance^2 matrix [64][512] ----------
    {
        const int wid = bid*8 + w;
        for (int p = wid*16; p < wid*16 + 16; ++p) {
            int rr = p >> 9;
            int kk = p & 511;
            const u64* u8p = (const u64*)(uq + (size_t)rr*HH);
            const f32x4* c4 = (const f32x4*)(cb + (size_t)kk*HH);
            float s = 0.0f;
            #pragma unroll
            for (int q = 0; q < 4; ++q) {
                u64 e0 = u8p[2*(l + q*64)];
                u64 e1 = u8p[2*(l + q*64) + 1];
                f32x4 b = c4[l + q*64];
                float a0 = __uint_as_float((u32)e0), a1 = __uint_as_float((u32)(e0>>32));
                float a2 = __uint_as_float((u32)e1), a3 = __uint_as_float((u32)(e1>>32));
                float d0 = a0-b[0], d1 = a1-b[1], d2 = a2-b[2], d3 = a3-b[3];
                s += d0*d0 + d1*d1 + d2*d2 + d3*d3;
            }
            #pragma unroll
            for (int off = 32; off > 0; off >>= 1) s += __shfl_xor(s, off, 64);
            if (l == 0) ST_AG(&dist[(size_t)rr*KCB + kk], s);
        }
    }
    bar_arrive(barT, bid, tid, 1);
    bar_wait(barT, bid, tid, 1);      // fence inside -> plain dist reads OK

    // ---------- argmin + emit outputs (blocks 0..63, one row each) ----------
    if (bid < BB) {
        const int rr = bid;
        if (tid < 64) {
            float best = 3.4e38f;
            int   bi   = 0;
            for (int kk = tid; kk < KCB; kk += 64) {
                float v = dist[(size_t)rr*KCB + kk];
                if (v < best) { best = v; bi = kk; }
            }
            #pragma unroll
            for (int off = 32; off > 0; off >>= 1) {
                float ovv = __shfl_xor(best, off, 64);
                int   oii = __shfl_xor(bi,   off, 64);
                if (ovv < best || (ovv == best && oii < bi)) { best = ovv; bi = oii; }
            }
            if (tid == 0) { sBest = bi; out[rr] = (float)bi; }
        }
        __syncthreads();
        const int bk = sBest;
        const f32x4* c4 = (const f32x4*)(cb + (size_t)bk*HH);
        f32x4*       q4 = (f32x4*)(qz + (size_t)rr*HH);
        for (int d = tid; d < HH/4; d += 512) q4[d] = c4[d];
    }
}

extern "C" void kernel_launch(void* const* d_in, const int* in_sizes, int n_in,
                              void* d_out, int out_size, void* d_ws, size_t ws_size,
                              hipStream_t stream) {
    const float* seq  = (const float*)d_in[0];
    const int*   nit  = (const int*)  d_in[1];
    const float* Wx   = (const float*)d_in[2];
    const float* Wh   = (const float*)d_in[3];
    const float* bias = (const float*)d_in[4];
    const float* cb   = (const float*)d_in[5];
    float* out = (float*)d_out;
    float* ws  = (float*)d_ws;

    void* args[] = { &seq, &nit, &Wx, &Wh, &bias, &cb, &out, &ws };
    hipLaunchCooperativeKernel((void*)lstm_vq, dim3(256), dim3(512), args, 0, stream);
}

// Round 14
// 2518.134 us; speedup vs baseline: 1.9026x; 1.4484x over previous
//
#include <hip/hip_runtime.h>
#include <hip/hip_cooperative_groups.h>

namespace cg = cooperative_groups;

typedef unsigned short u16;
typedef unsigned int   u32;
typedef unsigned long long u64;
typedef __attribute__((ext_vector_type(8))) short short8;
typedef __attribute__((ext_vector_type(4))) float f32x4;

#define BB   64
#define TT   256
#define II   512
#define HH   1024
#define KCB  512
#define GH   4096
#define KTOT 1536

#define BPAD 1544   // u16 elems per B row (3088 B stride)

// ws layout (float units):
//   [0 .. 6291456)        WT f32 [4096][1536] (dead after B-split)
//   [.. +131072)          h: 2 parities x (hi plane 65536 u16 + lo plane 65536 u16), SLOT-indexed
//   [.. +32768)           dist^2 [64][512] f32
//   [.. +2304)            barC: 8 chunks x (1 arrival + 8 goflag) lines x 32 u32
//   [.. +544)             barT: tail barrier, 17 lines x 32 u32
#define WS_WT   0
#define WS_H    (GH*KTOT)
#define WS_DIST (WS_H + 131072)
#define WS_BARC (WS_DIST + BB*KCB)
#define WS_BART (WS_BARC + 8*9*32)

#define LD_AG(p)   __hip_atomic_load((p), __ATOMIC_RELAXED, __HIP_MEMORY_SCOPE_AGENT)
#define ST_AG(p,v) __hip_atomic_store((p), (v), __ATOMIC_RELAXED, __HIP_MEMORY_SCOPE_AGENT)

__device__ __forceinline__ float sigf(float x){ return 1.0f/(1.0f+expf(-x)); }
__device__ __forceinline__ u16 bf16r(float f){ u32 u = __float_as_uint(f); u += 0x7FFFu + ((u>>16)&1u); return (u16)(u>>16); }
__device__ __forceinline__ float bf16f(u16 h){ return __uint_as_float(((u32)h)<<16); }

// ---- block-level tail barrier (rounds 5-13 proven) ----
__device__ __forceinline__ void bar_arrive(u32* bar, int bid, int tid, int e){
    asm volatile("s_waitcnt vmcnt(0)" ::: "memory");
    __syncthreads();
    if (tid == 0) {
        u32 old = atomicAdd(bar + (bid & 7) * 32, 1u);
        if (old == (u32)(e * 32 - 1)) {
            u32 old2 = atomicAdd(bar + 8 * 32, 1u);
            if (old2 == (u32)(e * 8 - 1)) {
                #pragma unroll
                for (int gg = 0; gg < 8; ++gg)
                    ST_AG(bar + (9 + gg) * 32, (u32)e);
            }
        }
    }
}
__device__ __forceinline__ void bar_wait(u32* bar, int bid, int tid, int e){
    if (tid == 0) {
        while ((int)LD_AG(bar + (9 + (bid & 7)) * 32) < e)
            __builtin_amdgcn_s_sleep(1);
        __builtin_amdgcn_fence(__ATOMIC_ACQUIRE, "agent");
    }
    __syncthreads();
}

__global__ __launch_bounds__(512, 1)
void lstm_vq(const float* __restrict__ seq, const int* __restrict__ nit,
             const float* __restrict__ Wx, const float* __restrict__ Wh,
             const float* __restrict__ bias, const float* __restrict__ cb,
             float* __restrict__ out, float* __restrict__ ws)
{
    cg::grid_group grid = cg::this_grid();
    __shared__ __align__(16) u16 bHi[16*BPAD];   // 49408 B
    __shared__ __align__(16) u16 bLo[16*BPAD];   // 49408 B
    __shared__ __align__(16) float exs[8*1024];  // 32768 B: [kslice][slot][col]
    __shared__ int permL[64], snitL[64];         // slot -> phys row / sorted nit
    __shared__ int sBest;

    const int tid = threadIdx.x;
    const int l   = tid & 63;
    const int w   = tid >> 6;        // 0..7 = k-slice / h-chunk owner
    const int bid = (int)blockIdx.x;

    float* WT   = ws + WS_WT;
    u16*   hbuf = (u16*)(ws + WS_H);             // 2 parities x 131072 u16
    float* dist = ws + WS_DIST;
    u32*   barC = (u32*)(ws + WS_BARC);
    u32*   barT = (u32*)(ws + WS_BART);
    float* qz   = out + BB;
    float* uq   = out + BB + BB*HH;

    if (bid == 0) {
        for (int i = tid; i < 8*9*32 + 17*32; i += 512) ST_AG(barC + i, 0u);
    }

    // ---------------- one-time: WT[zcol][k] = W[k][zcol] ----------------
    {
        const int c0 = bid * 16;
        float* tile = (float*)bHi;               // 16 x 68 f32 scratch (pre-B-split)
        for (int kt = 0; kt < KTOT; kt += 64) {
            __syncthreads();
            #pragma unroll
            for (int ii2 = 0; ii2 < 2; ++ii2) {
                int ky = ii2*32 + (tid>>4);      // 0..63
                int cx = tid & 15;
                int kk = kt + ky;
                float v = (kk < II) ? Wx[(size_t)kk*GH + c0 + cx]
                                    : Wh[(size_t)(kk-II)*GH + c0 + cx];
                tile[cx*68 + ky] = v;
            }
            __syncthreads();
            {
                int cx = tid >> 5;               // 0..15
                int k2 = (tid & 31) * 2;         // 0..62
                WT[(size_t)(c0+cx)*KTOT + kt + k2]     = tile[cx*68 + k2];
                WT[(size_t)(c0+cx)*KTOT + kt + k2 + 1] = tile[cx*68 + k2 + 1];
            }
        }
        grid.sync();   // full fences: WT visible; orders barrier resets
    }

    // ---------------- one-time: split this block's 16 z-cols into bHi/bLo ----------------
    {
        __syncthreads();
        const int n  = tid >> 5;                              // 0..15
        const int zc = ((n>>2)<<10) + (bid<<2) + (n&3);
        const float* wr = WT + (size_t)zc*KTOT;
        for (int k = (tid&31)*8; k < KTOT; k += 256) {
            f32x4 v0 = *(const f32x4*)(wr + k);
            f32x4 v1 = *(const f32x4*)(wr + k + 4);
            short8 ph, pl;
            #pragma unroll
            for (int e = 0; e < 8; ++e) {
                float fv = (e<4) ? v0[e] : v1[e-4];
                u16 hb = bf16r(fv);
                ph[e] = (short)hb;
                pl[e] = (short)bf16r(fv - bf16f(hb));
            }
            *(short8*)&bHi[n*BPAD + k] = ph;
            *(short8*)&bLo[n*BPAD + k] = pl;
        }
    }

    // ---------------- one-time: sorted-slot permutation (rows indep; sort by nit desc) ----------------
    {
        if (w == 0) {
            int ni = nit[l];
            int r  = 0;
            #pragma unroll
            for (int j = 0; j < 64; ++j) {
                int nj = __shfl(ni, j, 64);
                r += (nj > ni || (nj == ni && j < l)) ? 1 : 0;
            }
            permL[r] = l;         // slot r holds physical row l
            snitL[r] = ni;        // sorted (desc) nit
        }
        __syncthreads();
    }

    // ---------------- per-thread roles ----------------
    const int rEx  = (tid & 255) >> 2;           // gate slot (tid<256)
    const int ccEx = tid & 3;
    const int hcol = (bid<<2) + ccEx;
    const int prG  = permL[rEx];                 // physical row of my gate slot
    const int myNs = snitL[rEx];                 // its n_iter

    const int tmx0 = __builtin_amdgcn_readfirstlane(snitL[0]);   // = maxN
    const int tmx1 = __builtin_amdgcn_readfirstlane(snitL[16]);
    const int tmx2 = __builtin_amdgcn_readfirstlane(snitL[32]);
    const int tmx3 = __builtin_amdgcn_readfirstlane(snitL[48]);
    const int maxN = tmx0;

    // physical rows for my A-fragment lanes, per M-tile (slot = (mt<<4)+(l&15))
    const int aPh0 = permL[ 0 + (l&15)];
    const int aPh1 = permL[16 + (l&15)];
    const int aPh2 = permL[32 + (l&15)];
    const int aPh3 = permL[48 + (l&15)];

    const float bi_ = bias[hcol], bf_ = bias[HH+hcol], bg_ = bias[2*HH+hcol], bo_ = bias[3*HH+hcol];

    const int ag   = (l>>4)<<3;              // k sub-offset within K=32 slice
    const int bn   = l & 15;                 // B col this lane reads
    const int cprod = bid >> 5;              // chunk this block produces
    u32* myArr  = barC + cprod*288;                      // arrival line
    const u32* myFlag = barC + w*288 + (1 + (bid&7))*32; // wave w polls chunk w

    float cst = 0.0f;

#define XC(P, h0, h1, kab) { \
    short8 ph, pl; \
    _Pragma("unroll") for (int e=0;e<8;++e){ \
        float fv = (e<4) ? h0[e] : h1[e-4]; \
        u16 hb = bf16r(fv); ph[e]=(short)hb; pl[e]=(short)bf16r(fv - bf16f(hb)); } \
    int bo = bn*BPAD + (kab); \
    short8 bhv = *(const short8*)&bHi[bo]; \
    short8 blv = *(const short8*)&bLo[bo]; \
    P##0 = __builtin_amdgcn_mfma_f32_16x16x32_bf16(ph, bhv, P##0, 0,0,0); \
    P##1 = __builtin_amdgcn_mfma_f32_16x16x32_bf16(pl, bhv, P##1, 0,0,0); \
    P##2 = __builtin_amdgcn_mfma_f32_16x16x32_bf16(ph, blv, P##2, 0,0,0); }

#define HM(P, B, kab) { \
    int bo = bn*BPAD + (kab); \
    short8 bhv = *(const short8*)&bHi[bo]; \
    short8 blv = *(const short8*)&bLo[bo]; \
    P##0 = __builtin_amdgcn_mfma_f32_16x16x32_bf16(B##h, bhv, P##0, 0,0,0); \
    P##1 = __builtin_amdgcn_mfma_f32_16x16x32_bf16(B##l, bhv, P##1, 0,0,0); \
    P##2 = __builtin_amdgcn_mfma_f32_16x16x32_bf16(B##h, blv, P##2, 0,0,0); }

// x phase for M-tile: A row = PHYSICAL row (APH), k slice [64w, 64w+64)
#define XPH(P, APH) { \
    const float* xp_ = seq + (size_t)(APH)*(TT*II) + (size_t)t*II + (w<<6) + ag; \
    f32x4 x0 = *(const f32x4*)xp_,      x1 = *(const f32x4*)(xp_+4); \
    f32x4 x2 = *(const f32x4*)(xp_+32), x3 = *(const f32x4*)(xp_+36); \
    XC(P, x0, x1, (w<<6)+ag); \
    XC(P, x2, x3, (w<<6)+32+ag); }

// h phase for M-tile mt: A row = SLOT (h ring is slot-indexed), k slice = chunk w
#define HPH(P, mt) { \
    const u16* hp_ = hiP + (size_t)(((mt)<<4)+(l&15))*HH + (w<<7) + ag; \
    short8 h0h = *(const short8*)hp_,       h0l = *(const short8*)(hp_+65536); \
    short8 h1h = *(const short8*)(hp_+32),  h1l = *(const short8*)(hp_+32+65536); \
    short8 h2h = *(const short8*)(hp_+64),  h2l = *(const short8*)(hp_+64+65536); \
    short8 h3h = *(const short8*)(hp_+96),  h3l = *(const short8*)(hp_+96+65536); \
    HM(P, h0, 512+(w<<7)+ag);    HM(P, h1, 512+(w<<7)+32+ag); \
    HM(P, h2, 512+(w<<7)+64+ag); HM(P, h3, 512+(w<<7)+96+ag); }

#define EXW(P, mt) { \
    const int n_ = l & 15; \
    const int r0_ = ((mt)<<4) + ((l>>4)<<2); \
    float* e_ = exs + w*1024 + r0_*16 + n_; \
    _Pragma("unroll") for (int j=0;j<4;++j) \
        e_[j*16] = P##0[j] + P##1[j] + P##2[j]; }

    for (int t = 0; t <= maxN; ++t) {
        const u16* hiP = hbuf + (size_t)(t&1)*131072;
        u16*       hiN = hbuf + (size_t)(1-(t&1))*131072;
        u16*       loN = hiN + 65536;

        f32x4 z4 = {0.f,0.f,0.f,0.f};
        f32x4 aA0=z4,aA1=z4,aA2=z4, aB0=z4,aB1=z4,aB2=z4;
        f32x4 aC0=z4,aC1=z4,aC2=z4, aD0=z4,aD1=z4,aD2=z4;

        // ---- x GEMM: this wave's 64-k slice, ACTIVE tiles only (pre-wait) ----
        XPH(aA, aPh0)
        if (t <= tmx1) { XPH(aB, aPh1) }
        if (t <= tmx2) { XPH(aC, aPh2) }
        if (t <= tmx3) { XPH(aD, aPh3) }

        // ---- per-wave chunk wait, then h GEMM: chunk w, ACTIVE tiles ----
        if (t > 0) {
            while ((int)LD_AG(myFlag) < t) __builtin_amdgcn_s_sleep(1);
            HPH(aA,0)
            if (t <= tmx1) { HPH(aB,1) }
            if (t <= tmx2) { HPH(aC,2) }
            if (t <= tmx3) { HPH(aD,3) }
        }

        // ---- exchange: wave w writes its k-slice partials (active tiles) ----
        EXW(aA,0)
        if (t <= tmx1) { EXW(aB,1) }
        if (t <= tmx2) { EXW(aC,2) }
        if (t <= tmx3) { EXW(aD,3) }
        __syncthreads();

        // ---- gate (tid<256, active slots): sum 8 k-slices + bias ----
        if (tid < 256 && t <= myNs) {
            const float* e0 = exs + rEx*16 + ccEx;
            float z0 = bi_, z1 = bf_, z2 = bg_, z3 = bo_;
            #pragma unroll
            for (int ww = 0; ww < 8; ++ww) {
                const float* e_ = e0 + ww*1024;
                z0 += e_[0]; z1 += e_[4]; z2 += e_[8]; z3 += e_[12];
            }
            float iv = sigf(z0), fv = sigf(z1), gv = tanhf(z2), ov = sigf(z3);
            cst = fv*cst + iv*gv;
            float h = ov * tanhf(cst);
            u16 hb = bf16r(h);
            u16 lb = bf16r(h - bf16f(hb));
            ST_AG(&hiN[(size_t)rEx*HH + hcol], hb);     // slot-indexed
            ST_AG(&loN[(size_t)rEx*HH + hcol], lb);
            if (t == myNs) ST_AG(&uq[(size_t)prG*HH + hcol], h);  // physical row
        }

        // ---- arrive (chunk cprod) + one fence per block per step ----
        asm volatile("s_waitcnt vmcnt(0)" ::: "memory");
        __syncthreads();
        if (tid == 0) {
            u32 old = atomicAdd(myArr, 1u);
            if (old == (u32)((t+1)*32 - 1)) {
                #pragma unroll
                for (int g = 0; g < 8; ++g)
                    ST_AG(myArr + (1+g)*32, (u32)(t+1));
            }
            __builtin_amdgcn_fence(__ATOMIC_ACQUIRE, "agent");
        }
        __syncthreads();
    }

#undef XC
#undef HM
#undef XPH
#undef HPH
#undef EXW

    // ---------- tail: all chunks at epoch maxN+1, fence, then VQ ----------
    while ((int)LD_AG(myFlag) < maxN + 1) __builtin_amdgcn_s_sleep(1);
    __syncthreads();
    if (tid == 0) __builtin_amdgcn_fence(__ATOMIC_ACQUIRE, "agent");
    __syncthreads();

    // ---------- VQ: distance^2 matrix [64][512] ----------
    {
        const int wid = bid*8 + w;
        for (int p = wid*16; p < wid*16 + 16; ++p) {
            int rr = p >> 9;
            int kk = p & 511;
            const u64* u8p = (const u64*)(uq + (size_t)rr*HH);
            const f32x4* c4 = (const f32x4*)(cb + (size_t)kk*HH);
            float s = 0.0f;
            #pragma unroll
            for (int q = 0; q < 4; ++q) {
                u64 e0 = u8p[2*(l + q*64)];
                u64 e1 = u8p[2*(l + q*64) + 1];
                f32x4 b = c4[l + q*64];
                float a0 = __uint_as_float((u32)e0), a1 = __uint_as_float((u32)(e0>>32));
                float a2 = __uint_as_float((u32)e1), a3 = __uint_as_float((u32)(e1>>32));
                float d0 = a0-b[0], d1 = a1-b[1], d2 = a2-b[2], d3 = a3-b[3];
                s += d0*d0 + d1*d1 + d2*d2 + d3*d3;
            }
            #pragma unroll
            for (int off = 32; off > 0; off >>= 1) s += __shfl_xor(s, off, 64);
            if (l == 0) ST_AG(&dist[(size_t)rr*KCB + kk], s);
        }
    }
    bar_arrive(barT, bid, tid, 1);
    bar_wait(barT, bid, tid, 1);      // fence inside -> plain dist reads OK

    // ---------- argmin + emit outputs (blocks 0..63, one row each) ----------
    if (bid < BB) {
        const int rr = bid;
        if (tid < 64) {
            float best = 3.4e38f;
            int   bi   = 0;
            for (int kk = tid; kk < KCB; kk += 64) {
                float v = dist[(size_t)rr*KCB + kk];
                if (v < best) { best = v; bi = kk; }
            }
            #pragma unroll
            for (int off = 32; off > 0; off >>= 1) {
                float ovv = __shfl_xor(best, off, 64);
                int   oii = __shfl_xor(bi,   off, 64);
                if (ovv < best || (ovv == best && oii < bi)) { best = ovv; bi = oii; }
            }
            if (tid == 0) { sBest = bi; out[rr] = (float)bi; }
        }
        __syncthreads();
        const int bk = sBest;
        const f32x4* c4 = (const f32x4*)(cb + (size_t)bk*HH);
        f32x4*       q4 = (f32x4*)(qz + (size_t)rr*HH);
        for (int d = tid; d < HH/4; d += 512) q4[d] = c4[d];
    }
}

extern "C" void kernel_launch(void* const* d_in, const int* in_sizes, int n_in,
                              void* d_out, int out_size, void* d_ws, size_t ws_size,
                              hipStream_t stream) {
    const float* seq  = (const float*)d_in[0];
    const int*   nit  = (const int*)  d_in[1];
    const float* Wx   = (const float*)d_in[2];
    const float* Wh   = (const float*)d_in[3];
    const float* bias = (const float*)d_in[4];
    const float* cb   = (const float*)d_in[5];
    float* out = (float*)d_out;
    float* ws  = (float*)d_ws;

    void* args[] = { &seq, &nit, &Wx, &Wh, &bias, &cb, &out, &ws };
    hipLaunchCooperativeKernel((void*)lstm_vq, dim3(256), dim3(512), args, 0, stream);
}